// Round 1
// baseline (1727.863 us; speedup 1.0000x reference)
//
#include <hip/hip_runtime.h>
#include <hip/hip_bf16.h>
#include <math.h>

#define N_ROWS 131072
#define DIM 512
#define HID 1024
#define MEMC 512

typedef __attribute__((ext_vector_type(8))) short bf16x8;
typedef __attribute__((ext_vector_type(4))) float f32x4;

// ---------------------------------------------------------------------------
// Prep: cast weights to bf16 (transposed to [out_col][k] = B^T, K-contiguous)
// ---------------------------------------------------------------------------
__global__ void prep_weights(const float* __restrict__ up_w,   // [DIM][HID]
                             const float* __restrict__ down_w, // [HID][DIM]
                             const float* __restrict__ mb,     // [MEMC][DIM]
                             __hip_bfloat16* __restrict__ wtup, // [HID][DIM]
                             __hip_bfloat16* __restrict__ wtdn, // [DIM][HID]
                             __hip_bfloat16* __restrict__ cb)   // [MEMC][DIM]
{
    int i = blockIdx.x * blockDim.x + threadIdx.x;
    const int UP = DIM * HID;
    const int DN = HID * DIM;
    const int CB = MEMC * DIM;
    if (i < UP) {
        int n = i / DIM, k = i % DIM;              // wtup[n][k] = up_w[k][n]
        wtup[i] = __float2bfloat16(up_w[k * HID + n]);
    } else if (i < UP + DN) {
        int j = i - UP;
        int n = j / HID, k = j % HID;              // wtdn[n][k] = down_w[k][n]
        wtdn[j] = __float2bfloat16(down_w[k * DIM + n]);
    } else if (i < UP + DN + CB) {
        int j = i - UP - DN;
        cb[j] = __float2bfloat16(mb[j]);
    }
}

// ||c||^2 per code, one wave per code
__global__ void code_norms(const float* __restrict__ mb, float* __restrict__ cnorm)
{
    int wave = (blockIdx.x * blockDim.x + threadIdx.x) >> 6;
    int lane = threadIdx.x & 63;
    if (wave >= MEMC) return;
    float s = 0.f;
    #pragma unroll
    for (int t = 0; t < DIM / 64; ++t) {
        float v = mb[(size_t)wave * DIM + t * 64 + lane];
        s += v * v;
    }
    #pragma unroll
    for (int off = 32; off > 0; off >>= 1) s += __shfl_down(s, off);
    if (lane == 0) cnorm[wave] = s;
}

// ---------------------------------------------------------------------------
// x = input_emb + 0.1*neighbors + state_mu  -> x_f32 and x_bf16
// ---------------------------------------------------------------------------
__global__ void make_x(const float4* __restrict__ emb, const float4* __restrict__ nbr,
                       const float4* __restrict__ mu, float4* __restrict__ xf,
                       uint2* __restrict__ xb)
{
    int i = blockIdx.x * blockDim.x + threadIdx.x;  // over N*DIM/4
    float4 e = emb[i], n = nbr[i], m = mu[i & (DIM / 4 - 1)];
    float4 x;
    x.x = e.x + 0.1f * n.x + m.x;
    x.y = e.y + 0.1f * n.y + m.y;
    x.z = e.z + 0.1f * n.z + m.z;
    x.w = e.w + 0.1f * n.w + m.w;
    xf[i] = x;
    union { __hip_bfloat16 h[4]; uint2 u; } p;
    p.h[0] = __float2bfloat16(x.x); p.h[1] = __float2bfloat16(x.y);
    p.h[2] = __float2bfloat16(x.z); p.h[3] = __float2bfloat16(x.w);
    xb[i] = p.u;
}

// ---------------------------------------------------------------------------
// Tiled MFMA GEMM:  C[M][NC] = A[M][K] @ B[NC][K]^T   (bf16 in, f32 acc)
// 128x128 block, 4 waves (2x2), each wave 4x4 tiles of 16x16x32 MFMA.
// MODE 1: outb = bf16(silu(acc + bias))                  (h)
// MODE 2: v = resid + (acc + bias)*tanh(gate); outf=v, outb=bf16(v)  (x2)
// MODE 3: outf = acc                                     (raw scores dot)
// ---------------------------------------------------------------------------
#define BM 128
#define BN 128
#define BK 32

template <int MODE>
__global__ __launch_bounds__(256)
void gemm_bt(const __hip_bfloat16* __restrict__ A,
             const __hip_bfloat16* __restrict__ B,
             int M, int NC, int K,
             const float* __restrict__ bias,
             const float* resid,          // may alias outf (MODE 2)
             const float* __restrict__ gate,
             float* outf,
             __hip_bfloat16* __restrict__ outb)
{
    __shared__ __align__(16) __hip_bfloat16 As[BM * BK];
    __shared__ __align__(16) __hip_bfloat16 Bs[BN * BK];

    const int tid  = threadIdx.x;
    const int w    = tid >> 6;
    const int lane = tid & 63;
    const int quad = lane >> 4;
    const int l16  = lane & 15;
    const int wrow = w >> 1, wcol = w & 1;

    const int rowA0 = blockIdx.y * BM;
    const int rowB0 = blockIdx.x * BN;

    f32x4 acc[4][4];
    #pragma unroll
    for (int i = 0; i < 4; ++i)
        #pragma unroll
        for (int j = 0; j < 4; ++j)
            acc[i][j] = (f32x4){0.f, 0.f, 0.f, 0.f};

    const int kTiles = K / BK;
    for (int kt = 0; kt < kTiles; ++kt) {
        const int k0 = kt * BK;
        #pragma unroll
        for (int c = 0; c < 2; ++c) {
            int chunk = w * 2 + c;              // 0..7, each covers 1KB of tile
            int flat  = chunk * 512;            // element offset of chunk base
            int lflat = flat + lane * 8;        // this lane's 8 elements
            int row   = lflat >> 5;             // tile row (32 elem per row)
            int col   = lflat & 31;
            __builtin_amdgcn_global_load_lds(
                (const __attribute__((address_space(1))) void*)(A + (size_t)(rowA0 + row) * K + k0 + col),
                (__attribute__((address_space(3))) void*)(As + flat),
                16, 0, 0);
            __builtin_amdgcn_global_load_lds(
                (const __attribute__((address_space(1))) void*)(B + (size_t)(rowB0 + row) * K + k0 + col),
                (__attribute__((address_space(3))) void*)(Bs + flat),
                16, 0, 0);
        }
        __syncthreads();   // drains vmcnt before barrier -> LDS tiles ready

        bf16x8 av[4], bv[4];
        #pragma unroll
        for (int i = 0; i < 4; ++i)
            av[i] = *(const bf16x8*)&As[(wrow * 64 + i * 16 + l16) * BK + quad * 8];
        #pragma unroll
        for (int j = 0; j < 4; ++j)
            bv[j] = *(const bf16x8*)&Bs[(wcol * 64 + j * 16 + l16) * BK + quad * 8];
        #pragma unroll
        for (int i = 0; i < 4; ++i)
            #pragma unroll
            for (int j = 0; j < 4; ++j)
                acc[i][j] = __builtin_amdgcn_mfma_f32_16x16x32_bf16(av[i], bv[j], acc[i][j], 0, 0, 0);
        __syncthreads();   // all waves done reading LDS before next stage
    }

    float tg = 0.f;
    if (MODE == 2) tg = tanhf(gate[0]);

    #pragma unroll
    for (int i = 0; i < 4; ++i) {
        #pragma unroll
        for (int j = 0; j < 4; ++j) {
            #pragma unroll
            for (int r = 0; r < 4; ++r) {
                int grow = rowA0 + wrow * 64 + i * 16 + quad * 4 + r;
                int gcol = rowB0 + wcol * 64 + j * 16 + l16;
                float v = acc[i][j][r];
                size_t oidx = (size_t)grow * NC + gcol;
                if (MODE == 1) {
                    v += bias[gcol];
                    v = v / (1.f + expf(-v));          // silu
                    outb[oidx] = __float2bfloat16(v);
                } else if (MODE == 2) {
                    v = resid[oidx] + (v + bias[gcol]) * tg;
                    outf[oidx] = v;
                    outb[oidx] = __float2bfloat16(v);
                } else {
                    outf[oidx] = v;
                }
            }
        }
    }
}

// ---------------------------------------------------------------------------
// Per-row argmin over codes + gather + nan_to_num + norm clamp. 1 wave / row.
// scores holds raw dot products x2.c; true score = -2*dot + ||c||^2
// ---------------------------------------------------------------------------
__global__ void argmin_final(const float* __restrict__ scores, // [N][MEMC]
                             const float* __restrict__ cnorm,  // [MEMC]
                             const float* __restrict__ x2,     // [N][DIM]
                             const float* __restrict__ mb,     // [MEMC][DIM] f32
                             float* __restrict__ out)          // [N][DIM]
{
    int row  = (blockIdx.x * blockDim.x + threadIdx.x) >> 6;
    int lane = threadIdx.x & 63;
    if (row >= N_ROWS) return;

    float best = INFINITY; int bidx = 0x7fffffff;
    #pragma unroll
    for (int t = 0; t < MEMC / 64; ++t) {
        int c = t * 64 + lane;
        float s = -2.f * scores[(size_t)row * MEMC + c] + cnorm[c];
        if (s < best || (s == best && c < bidx)) { best = s; bidx = c; }
    }
    #pragma unroll
    for (int off = 32; off > 0; off >>= 1) {
        float ob = __shfl_down(best, off);
        int   oi = __shfl_down(bidx, off);
        if (ob < best || (ob == best && oi < bidx)) { best = ob; bidx = oi; }
    }
    bidx = __shfl(bidx, 0);

    const float* code = mb + (size_t)bidx * DIM;
    float v[DIM / 64];
    float ss = 0.f;
    #pragma unroll
    for (int t = 0; t < DIM / 64; ++t) {
        int c = t * 64 + lane;
        float x = x2[(size_t)row * DIM + c] + 0.05f * code[c];
        if (x != x) x = 0.f;                       // nan -> 0
        else if (x == INFINITY) x = 1.f;
        else if (x == -INFINITY) x = -1.f;
        v[t] = x;
        ss += x * x;
    }
    #pragma unroll
    for (int off = 32; off > 0; off >>= 1) ss += __shfl_down(ss, off);
    ss = __shfl(ss, 0);
    float nrm = sqrtf(ss);
    float scale = (nrm > 10.f) ? (10.f / fmaxf(nrm, 1e-6f)) : 1.f;
    #pragma unroll
    for (int t = 0; t < DIM / 64; ++t)
        out[(size_t)row * DIM + t * 64 + lane] = v[t] * scale;
}

// ---------------------------------------------------------------------------
extern "C" void kernel_launch(void* const* d_in, const int* in_sizes, int n_in,
                              void* d_out, int out_size, void* d_ws, size_t ws_size,
                              hipStream_t stream)
{
    const float* input_emb = (const float*)d_in[0];
    const float* neighbors = (const float*)d_in[1];
    const float* state_mu  = (const float*)d_in[2];
    const float* up_w      = (const float*)d_in[3];
    const float* up_b      = (const float*)d_in[4];
    const float* down_w    = (const float*)d_in[5];
    const float* down_b    = (const float*)d_in[6];
    const float* gate      = (const float*)d_in[7];
    const float* mbook     = (const float*)d_in[8];
    float* out = (float*)d_out;

    char* w = (char*)d_ws;
    size_t off = 0;
    float* x_f32 = (float*)(w + off);                 // x, then x2 (in-place)
    off += (size_t)N_ROWS * DIM * 4;                  // 268 MB
    __hip_bfloat16* xb = (__hip_bfloat16*)(w + off);  // x bf16, then x2 bf16
    off += (size_t)N_ROWS * DIM * 2;                  // 134 MB
    char* hbuf = w + off;                             // h bf16, then scores f32
    off += (size_t)N_ROWS * HID * 2;                  // 268 MB
    __hip_bfloat16* h_bf16 = (__hip_bfloat16*)hbuf;
    float* scores = (float*)hbuf;
    __hip_bfloat16* wtup = (__hip_bfloat16*)(w + off); off += (size_t)HID * DIM * 2;
    __hip_bfloat16* wtdn = (__hip_bfloat16*)(w + off); off += (size_t)DIM * HID * 2;
    __hip_bfloat16* cb   = (__hip_bfloat16*)(w + off); off += (size_t)MEMC * DIM * 2;
    float* cnorm = (float*)(w + off);                  off += MEMC * 4;

    prep_weights<<<(DIM * HID + HID * DIM + MEMC * DIM + 255) / 256, 256, 0, stream>>>(
        up_w, down_w, mbook, wtup, wtdn, cb);
    code_norms<<<MEMC * 64 / 256, 256, 0, stream>>>(mbook, cnorm);
    make_x<<<(N_ROWS * DIM / 4) / 256, 256, 0, stream>>>(
        (const float4*)input_emb, (const float4*)neighbors, (const float4*)state_mu,
        (float4*)x_f32, (uint2*)xb);

    // h = silu(x @ W_up + b_up)           [N][HID] bf16
    gemm_bt<1><<<dim3(HID / BN, N_ROWS / BM), 256, 0, stream>>>(
        xb, wtup, N_ROWS, HID, DIM, up_b, nullptr, nullptr, nullptr, h_bf16);
    // x2 = x + (h @ W_down + b_down)*tanh(gate)   (f32 in-place + bf16)
    gemm_bt<2><<<dim3(DIM / BN, N_ROWS / BM), 256, 0, stream>>>(
        h_bf16, wtdn, N_ROWS, DIM, HID, down_b, x_f32, gate, x_f32, xb);
    // raw dots = x2 @ C^T                  [N][MEMC] f32 (into h buffer)
    gemm_bt<3><<<dim3(MEMC / BN, N_ROWS / BM), 256, 0, stream>>>(
        xb, cb, N_ROWS, MEMC, DIM, nullptr, nullptr, nullptr, scores, nullptr);

    argmin_final<<<N_ROWS * 64 / 256, 256, 0, stream>>>(scores, cnorm, x_f32, mbook, out);
}